// Round 1
// baseline (246.416 us; speedup 1.0000x reference)
//
#include <hip/hip_runtime.h>

// Problem constants (fixed by the reference)
#define NGRAPH 16
#define NPG    4096
#define KCL    64
#define DF     128
#define NTOT   (NGRAPH*NPG)     // 65536
#define NEDGE  (NTOT*16)        // 1048576

// output layout (floats)
//   out       [0, 131072)
//   out_adj   [131072, 196608)
//   link_loss 196608
//   entropy   196609
//   batch     [196610, 197634)
//   batch_ptr [197634, 197651)

// ws layout (bytes)
//   clus   uint8[65536]      @ 0
//   counts int[1024]         @ 65536
//   cross  float[16]         @ 69632
//   asq    float[16]         @ 69696

__global__ __launch_bounds__(256) void assign_scatter_kernel(
    const float* __restrict__ x, const float* __restrict__ W,
    const float* __restrict__ bias, const float* __restrict__ gum,
    unsigned char* __restrict__ clus, int* __restrict__ counts,
    float* __restrict__ out)
{
    __shared__ __align__(16) float xs[64 * 132];   // 64 nodes x 128, pad 132
    __shared__ float cand_v[4][64];
    __shared__ int   cand_k[4][64];
    __shared__ int   ck[64];

    const int tid  = threadIdx.x;
    const int wave = tid >> 6;
    const int lane = tid & 63;
    const int n0   = blockIdx.x * 64;     // first node of this block
    const int bg   = blockIdx.x >> 6;     // graph id (64 blocks per graph)

    // ---- stage x tile: 64 rows x 128 floats, coalesced float4 ----
    {
        const float4* xg = (const float4*)(x + (size_t)n0 * DF);
        #pragma unroll
        for (int i = 0; i < 8; ++i) {
            int j4 = tid + i * 256;     // float4 index within tile
            int j  = j4 << 2;
            float4 v = xg[j4];
            *(float4*)&xs[(j >> 7) * 132 + (j & 127)] = v;
        }
    }
    __syncthreads();

    // ---- logits for 16 k's per wave, lane = node ----
    const int n  = lane;
    const int k0 = __builtin_amdgcn_readfirstlane(wave << 4);  // wave-uniform

    float acc[16];
    #pragma unroll
    for (int kk = 0; kk < 16; ++kk) acc[kk] = bias[k0 + kk];

    #pragma unroll 4
    for (int dc = 0; dc < 32; ++dc) {
        float4 xv = *(const float4*)&xs[n * 132 + (dc << 2)];
        const float* wp = W + (dc << 8) + k0;    // W[(4*dc)*64 + k0]
        #pragma unroll
        for (int kk = 0; kk < 16; ++kk) {
            float a = acc[kk];
            a = fmaf(xv.x, wp[kk],        a);
            a = fmaf(xv.y, wp[64  + kk],  a);
            a = fmaf(xv.z, wp[128 + kk],  a);
            a = fmaf(xv.w, wp[192 + kk],  a);
            acc[kk] = a;
        }
    }

    // ---- gumbel noise + per-wave argmax (first-max tie-break, k ascending) ----
    const float* gp = gum + ((size_t)(n0 + n) << 6) + k0;
    float best = -3.4e38f; int bestk = k0;
    #pragma unroll
    for (int q = 0; q < 4; ++q) {
        float4 u = *(const float4*)(gp + (q << 2));
        float uv[4] = {u.x, u.y, u.z, u.w};
        #pragma unroll
        for (int r = 0; r < 4; ++r) {
            float g = -logf(-logf(uv[r]));
            float v = acc[(q << 2) + r] + g;
            if (v > best) { best = v; bestk = k0 + (q << 2) + r; }
        }
    }
    cand_v[wave][n] = best;
    cand_k[wave][n] = bestk;
    __syncthreads();

    // ---- combine across the 4 waves (k-chunk ascending => global first-max) ----
    if (tid < 64) {
        float bv = cand_v[0][tid]; int bk = cand_k[0][tid];
        #pragma unroll
        for (int w2 = 1; w2 < 4; ++w2) {
            float v = cand_v[w2][tid];
            if (v > bv) { bv = v; bk = cand_k[w2][tid]; }
        }
        clus[n0 + tid] = (unsigned char)bk;
        ck[tid] = bk;
        atomicAdd(&counts[(bg << 6) + bk], 1);
    }
    __syncthreads();

    // ---- scatter: out[(bg*64 + c), :] += x[n, :] ----
    const int d    = tid & 127;
    const int half = tid >> 7;          // uniform within a wave
    #pragma unroll 4
    for (int it = 0; it < 32; ++it) {
        int nn = (it << 1) + half;
        int c  = ck[nn];
        atomicAdd(&out[(size_t)((bg << 6) + c) * DF + d], xs[nn * 132 + d]);
    }
}

__global__ __launch_bounds__(256) void edge_kernel(
    const int* __restrict__ ei, const float* __restrict__ ew,
    const unsigned char* __restrict__ clus,
    float* __restrict__ out_adj, float* __restrict__ cross,
    float* __restrict__ asq)
{
    __shared__ float red[2][4];
    const int e  = blockIdx.x * 256 + threadIdx.x;
    const int bg = blockIdx.x >> 8;          // 256 blocks per graph

    const int   s = ei[e];
    const int   d = ei[NEDGE + e];
    const float w = ew[e];
    const int  ks = clus[s];
    const int  kd = clus[d];

    atomicAdd(&out_adj[(bg << 12) + (ks << 6) + kd], w);

    float c = (ks == kd) ? w : 0.0f;
    float q = w * w;
    #pragma unroll
    for (int off = 32; off > 0; off >>= 1) {
        c += __shfl_down(c, off);
        q += __shfl_down(q, off);
    }
    const int lane = threadIdx.x & 63, wv = threadIdx.x >> 6;
    if (lane == 0) { red[0][wv] = c; red[1][wv] = q; }
    __syncthreads();
    if (threadIdx.x == 0) {
        float cs = red[0][0] + red[0][1] + red[0][2] + red[0][3];
        float qs = red[1][0] + red[1][1] + red[1][2] + red[1][3];
        atomicAdd(&cross[bg], cs);
        atomicAdd(&asq[bg],  qs);
    }
}

__global__ __launch_bounds__(1024) void finalize_kernel(
    const int* __restrict__ counts, const float* __restrict__ cross,
    const float* __restrict__ asq, float* __restrict__ out)
{
    __shared__ float links[16];
    const int tid = threadIdx.x;
    const int wv = tid >> 6, lane = tid & 63;   // wave wv handles graph wv

    float c  = (float)counts[(wv << 6) + lane];
    float s2 = c * c;
    #pragma unroll
    for (int off = 32; off > 0; off >>= 1) s2 += __shfl_down(s2, off);
    if (lane == 0) {
        float v = asq[wv] - 2.0f * cross[wv] + s2;
        links[wv] = sqrtf(fmaxf(v, 0.0f)) * (1.0f / 65536.0f);
    }
    __syncthreads();
    if (tid == 0) {
        float m = 0.0f;
        #pragma unroll
        for (int i = 0; i < 16; ++i) m += links[i];
        out[196608] = m * (1.0f / 16.0f);   // link_loss
        out[196609] = 0.0f;                 // entropy_loss (exactly 0 for one-hot)
    }
    // batch = repeat(arange(16), 64)
    out[196610 + tid] = (float)(tid >> 6);
    // batch_ptr_out = arange(17) * 64
    if (tid < 17) out[197634 + tid] = (float)(tid * 64);
}

extern "C" void kernel_launch(void* const* d_in, const int* in_sizes, int n_in,
                              void* d_out, int out_size, void* d_ws, size_t ws_size,
                              hipStream_t stream) {
    const float* x    = (const float*)d_in[0];
    const float* W    = (const float*)d_in[1];
    const float* bias = (const float*)d_in[2];
    const float* ew   = (const float*)d_in[3];
    const float* gum  = (const float*)d_in[4];
    const int*   ei   = (const int*)  d_in[5];
    // d_in[6] = batch_ptr (int64) — unused, graphs are equal-sized

    float* out = (float*)d_out;

    unsigned char* clus  = (unsigned char*)d_ws;
    int*   counts = (int*)  ((char*)d_ws + 65536);
    float* cross  = (float*)((char*)d_ws + 69632);
    float* asq    = (float*)((char*)d_ws + 69696);

    // zero the accumulated regions (harness poisons d_out/d_ws with 0xAA)
    hipMemsetAsync(d_out, 0, (size_t)196608 * sizeof(float), stream);          // out + out_adj
    hipMemsetAsync((char*)d_ws + 65536, 0, 4096 + 128, stream);                // counts + cross + asq

    assign_scatter_kernel<<<NTOT / 64, 256, 0, stream>>>(
        x, W, bias, gum, clus, counts, out);

    edge_kernel<<<NEDGE / 256, 256, 0, stream>>>(
        ei, ew, clus, out + 131072, cross, asq);

    finalize_kernel<<<1, 1024, 0, stream>>>(counts, cross, asq, out);
}